// Round 4
// baseline (185.306 us; speedup 1.0000x reference)
//
#include <hip/hip_runtime.h>
#include <math.h>

#define BB 512
#define DD 512
#define CC 100000
#define CCPAD 100096          // 782 * 128
#define MARGIN 0.2f
#define CLIP_EPS 1e-8f
#define NCOLT 782             // class tiles of 128

typedef short short8 __attribute__((ext_vector_type(8)));
typedef float f32x4  __attribute__((ext_vector_type(4)));

// ---- workspace layout (byte offsets) ----
#define XNB_BYTES   524288u                       // bf16[512*512]
#define P_BYTES     1601536u                      // float[782*512]
#define PBASE       XNB_BYTES

__device__ inline unsigned short f2bf(float a) {
    unsigned u = __builtin_bit_cast(unsigned, a);
    return (unsigned short)((u + 0x7fffu + ((u >> 16) & 1u)) >> 16);
}
__device__ inline unsigned pk2(float a, float b) {
    return (unsigned)f2bf(a) | ((unsigned)f2bf(b) << 16);
}
__device__ inline float bf2f(unsigned short h) {
    unsigned u = ((unsigned)h) << 16;
    return __builtin_bit_cast(float, u);
}
// swizzled element offset within a [128][32] bf16 tile; kk multiple of 8
__device__ inline int soff(int row, int kk) {
    return row * 32 + (kk ^ (((row >> 1) & 3) << 3));
}

// ---------------- kernel 1: normalize x rows -> bf16, zero out ----------------
__global__ __launch_bounds__(256) void k_norm_x(const float* __restrict__ x,
                                                unsigned short* __restrict__ XNB,
                                                float* __restrict__ out) {
    int row = blockIdx.x, tid = threadIdx.x;
    float v0 = x[row * DD + tid];
    float v1 = x[row * DD + tid + 256];
    float ss = v0 * v0 + v1 * v1;
    for (int m = 1; m < 64; m <<= 1) ss += __shfl_xor(ss, m, 64);
    __shared__ float sm[4];
    int wid = tid >> 6, lane = tid & 63;
    if (lane == 0) sm[wid] = ss;
    __syncthreads();
    float inv = 1.0f / fmaxf(sqrtf(sm[0] + sm[1] + sm[2] + sm[3]), 1e-12f);
    XNB[row * DD + tid]       = f2bf(v0 * inv);
    XNB[row * DD + tid + 256] = f2bf(v1 * inv);
    if (row == 0 && tid == 0) out[0] = 0.0f;
}

// -------- kernel 2: fused (normalize-W -> bf16 MFMA logits -> softmax stats) --------
// 1D grid 3128, XCD-chunked swizzle. 4 waves (2x2), tile 128 classes x 128 batch.
// K=512 in 8 iters of BK=64 (two [128x32] sub-tiles). W read as f32 ONCE, with
// per-row sum(w^2) fused into staging; winv applied in epilogue.
// A = W (classes, reg-staged f32->bf16), B = XNB (batch, global_load_lds).
__global__ __launch_bounds__(256) void k_gemm_f(const float* __restrict__ w,
                                                const unsigned short* __restrict__ XNB,
                                                const float* __restrict__ rescale_p,
                                                float* __restrict__ ZP,
                                                float* __restrict__ S2P,
                                                float* __restrict__ S3P) {
    __shared__ __align__(16) unsigned short Wt[2][128 * 32];
    __shared__ __align__(16) unsigned short Xs[2][128 * 32];
    __shared__ float st[2][2][64][3];   // [batch half][class half][batch row][stat]
    __shared__ float wsum[128];

    int h = blockIdx.x;
    int logical = (h & 7) * 391 + (h >> 3);   // 3128 = 8*391, bijective
    int ct = logical >> 2;                    // class tile 0..781
    int bt = logical & 3;                     // batch tile 0..3

    int tid = threadIdx.x;
    int lane = tid & 63, wid = tid >> 6;
    int wr = wid >> 1, wc = wid & 1;          // wr: class half, wc: batch half
    float rescale = rescale_p[0];

    // ---- staging geometry ----
    int srow = tid & 127, half = tid >> 7;    // W: thread owns row srow, k-half `half`
    int cg = ct * 128 + srow;
    int cgc = cg < CC ? cg : CC - 1;
    const float4* wrow = (const float4*)(w + (size_t)cgc * DD);  // 128 float4 per row

    // X gload_lds: per sub-tile s, issue i: wave-uniform LDS dest, per-lane swizzled src
    int xrl0 = (wid * 16) + (lane >> 2);      // issue i adds i*64
    int xc   = lane & 3;

    // fragment read offsets (within a [128x32] tile)
    int ro[4], co[4];
#pragma unroll
    for (int i = 0; i < 4; i++) {
        ro[i] = soff(wr * 64 + i * 16 + (lane & 15), (lane >> 4) * 8);  // class (A)
        co[i] = soff(wc * 64 + i * 16 + (lane & 15), (lane >> 4) * 8);  // batch (B)
    }

    f32x4 acc[4][4];
#pragma unroll
    for (int i = 0; i < 4; i++)
#pragma unroll
        for (int j = 0; j < 4; j++) acc[i][j] = (f32x4){0.f, 0.f, 0.f, 0.f};

    float4 wrg[8];        // prefetched f32 W chunk (32 elems = this thread's half-row slab)
    float  swacc = 0.f;   // fused sum(w^2) over this thread's slab

    auto STAGE_X = [&](int kt) {
#pragma unroll
        for (int s = 0; s < 2; ++s)
#pragma unroll
            for (int i = 0; i < 2; ++i) {
                int rl = i * 64 + xrl0;
                int sc = xc ^ ((rl >> 1) & 3);
                const unsigned short* src =
                    XNB + (size_t)(bt * 128 + rl) * DD + kt * 64 + s * 32 + sc * 8;
                unsigned short* dst = &Xs[s][(i * 64 + wid * 16) * 32];
                __builtin_amdgcn_global_load_lds(
                    (const __attribute__((address_space(1))) void*)src,
                    (__attribute__((address_space(3))) void*)dst, 16, 0, 0);
            }
    };
    auto LOAD_W = [&](int kt) {
#pragma unroll
        for (int j = 0; j < 8; ++j) wrg[j] = wrow[kt * 16 + half * 8 + j];
    };
    auto STORE_W = [&]() {
#pragma unroll
        for (int j = 0; j < 4; ++j) {
            float4 a = wrg[2 * j], b = wrg[2 * j + 1];
            swacc += a.x*a.x + a.y*a.y + a.z*a.z + a.w*a.w
                   + b.x*b.x + b.y*b.y + b.z*b.z + b.w*b.w;
            uint4 v;
            v.x = pk2(a.x, a.y); v.y = pk2(a.z, a.w);
            v.z = pk2(b.x, b.y); v.w = pk2(b.z, b.w);
            *(uint4*)&Wt[half][soff(srow, j * 8)] = v;
        }
    };
    auto COMPUTE = [&]() {
#pragma unroll
        for (int s = 0; s < 2; ++s) {
            short8 a[4], b[4];
#pragma unroll
            for (int i = 0; i < 4; i++) a[i] = *(const short8*)&Wt[s][ro[i]];
#pragma unroll
            for (int i = 0; i < 4; i++) b[i] = *(const short8*)&Xs[s][co[i]];
#pragma unroll
            for (int i = 0; i < 4; i++)
#pragma unroll
                for (int j = 0; j < 4; j++)
                    acc[i][j] = __builtin_amdgcn_mfma_f32_16x16x32_bf16(a[i], b[j], acc[i][j], 0, 0, 0);
        }
    };

    // ---- prologue: fill tiles for kt=0, prefetch W for kt=1 ----
    LOAD_W(0);
    STAGE_X(0);
    STORE_W();
    LOAD_W(1);
    __syncthreads();

    // ---- main loop: 8 iters, 2 barriers each, 32 MFMA per barrier pair ----
    for (int kt = 0; kt < 8; ++kt) {
        COMPUTE();
        __syncthreads();                 // all waves done reading LDS
        if (kt < 7) {
            STAGE_X(kt + 1);             // async bf16 X -> LDS (pre-swizzled source)
            STORE_W();                   // pk2 + swizzled ds_write (data for kt+1)
            if (kt < 6) LOAD_W(kt + 2);  // prefetch next W slab
            __syncthreads();             // tiles ready (drains vmcnt/lgkm)
        }
    }

    // ---- combine per-row sum(w^2) across the two half-row threads ----
    __syncthreads();
    if (half == 0) wsum[srow] = swacc;
    __syncthreads();
    if (half == 1) wsum[srow] += swacc;
    __syncthreads();

    // ---- epilogue: winv -> cos -> clip -> exp stats (classes in-thread) ----
    float mref = fabsf(rescale);
    const float L2E = 1.44269504f;
    float rs = rescale * L2E, mb = mref * L2E;
    float zz[4] = {0.f,0.f,0.f,0.f}, q2[4] = {0.f,0.f,0.f,0.f}, q3[4] = {0.f,0.f,0.f,0.f};
#pragma unroll
    for (int mi = 0; mi < 4; mi++) {
#pragma unroll
        for (int reg = 0; reg < 4; reg++) {
            int cl = wr * 64 + mi * 16 + (lane >> 4) * 4 + reg;   // local class row
            int c  = ct * 128 + cl;
            float mask = (c < CC) ? 1.0f : 0.0f;
            float winv = 1.0f / fmaxf(sqrtf(wsum[cl]), 1e-12f);   // LDS broadcast read
#pragma unroll
            for (int ni = 0; ni < 4; ni++) {
                float cosv = acc[mi][ni][reg] * winv;
                cosv = fminf(fmaxf(cosv, -1.0f + CLIP_EPS), 1.0f - CLIP_EPS);
                float e = exp2f(fmaf(cosv, rs, -mb)) * mask;
                float e2 = e * e;
                zz[ni] += e;
                q2[ni] += e2;
                q3[ni] = fmaf(e2, e, q3[ni]);
            }
        }
    }
#pragma unroll
    for (int msk = 16; msk < 64; msk <<= 1) {
#pragma unroll
        for (int ni = 0; ni < 4; ni++) {
            zz[ni] += __shfl_xor(zz[ni], msk, 64);
            q2[ni] += __shfl_xor(q2[ni], msk, 64);
            q3[ni] += __shfl_xor(q3[ni], msk, 64);
        }
    }
    if (lane < 16) {
#pragma unroll
        for (int ni = 0; ni < 4; ni++) {
            st[wc][wr][ni * 16 + lane][0] = zz[ni];
            st[wc][wr][ni * 16 + lane][1] = q2[ni];
            st[wc][wr][ni * 16 + lane][2] = q3[ni];
        }
    }
    __syncthreads();
    if (tid < 128) {
        int bh = tid >> 6, bl = tid & 63;
        float Z  = st[bh][0][bl][0] + st[bh][1][bl][0];
        float S2 = st[bh][0][bl][1] + st[bh][1][bl][1];
        float S3 = st[bh][0][bl][2] + st[bh][1][bl][2];
        size_t gi = (size_t)ct * BB + bt * 128 + tid;
        ZP[gi] = Z; S2P[gi] = S2; S3P[gi] = S3;
    }
}

// ---------------- kernel 3: combine partials, margin fixup, loss ----------------
__global__ __launch_bounds__(256) void k_final(const float* __restrict__ w,
                                               const int* __restrict__ y,
                                               const float* __restrict__ rescale_p,
                                               const unsigned short* __restrict__ XNB,
                                               const float* __restrict__ ZP,
                                               const float* __restrict__ S2P,
                                               const float* __restrict__ S3P,
                                               float* __restrict__ out) {
    int b = blockIdx.x, tid = threadIdx.x;
    int yb = y[b];

    float d0 = 0.f, q0 = 0.f;
#pragma unroll
    for (int i = 0; i < 2; i++) {
        int idx = tid + i * 256;
        float xv = bf2f(XNB[b * DD + idx]);
        float wvv = w[(size_t)yb * DD + idx];
        d0 = fmaf(xv, wvv, d0);
        q0 = fmaf(wvv, wvv, q0);
    }
    for (int m = 1; m < 64; m <<= 1) { d0 += __shfl_xor(d0, m, 64); q0 += __shfl_xor(q0, m, 64); }
    __shared__ float sd[4], sq[4], szs[4], s2s[4], s3s[4];
    int wid = tid >> 6, lane = tid & 63;
    if (lane == 0) { sd[wid] = d0; sq[wid] = q0; }

    float rz = 0.f, r2 = 0.f, r3 = 0.f;
    for (int ch = tid; ch < NCOLT; ch += 256) {
        size_t gi = (size_t)ch * BB + b;
        rz += ZP[gi]; r2 += S2P[gi]; r3 += S3P[gi];
    }
    for (int m = 1; m < 64; m <<= 1) {
        rz += __shfl_xor(rz, m, 64);
        r2 += __shfl_xor(r2, m, 64);
        r3 += __shfl_xor(r3, m, 64);
    }
    if (lane == 0) { szs[wid] = rz; s2s[wid] = r2; s3s[wid] = r3; }
    __syncthreads();

    if (tid == 0) {
        float Z  = szs[0] + szs[1] + szs[2] + szs[3];
        float S2 = s2s[0] + s2s[1] + s2s[2] + s2s[3];
        float S3 = s3s[0] + s3s[1] + s3s[2] + s3s[3];
        float dot = sd[0] + sd[1] + sd[2] + sd[3];
        float ssq = sq[0] + sq[1] + sq[2] + sq[3];
        float rescale = rescale_p[0];
        float mref = fabsf(rescale);
        float winv = 1.0f / fmaxf(sqrtf(ssq), 1e-12f);
        float fc = fminf(fmaxf(dot * winv, -1.0f + CLIP_EPS), 1.0f - CLIP_EPS);
        float su = rescale * fc;
        float fcm = fc * cosf(MARGIN) - sqrtf(fmaxf(1.0f - fc * fc, 0.0f)) * sinf(MARGIN);
        float smv = rescale * fcm;
        float eU = __expf(su - mref), eM = __expf(smv - mref);
        Z  += eM - eU;
        S2 += eM * eM - eU * eU;
        S3 += eM * eM * eM - eU * eU * eU;
        float py = eM / Z;
        float sumexp = (float)CC + 1.0f + S2 / (2.0f * Z * Z) + S3 / (6.0f * Z * Z * Z);
        float nll = logf(sumexp) - py;
        atomicAdd(out, nll * (1.0f / (float)BB));
    }
}

extern "C" void kernel_launch(void* const* d_in, const int* in_sizes, int n_in,
                              void* d_out, int out_size, void* d_ws, size_t ws_size,
                              hipStream_t stream) {
    const float* x       = (const float*)d_in[0];
    const int*   y       = (const int*)  d_in[1];
    const float* w       = (const float*)d_in[2];
    const float* rescale = (const float*)d_in[3];
    float* out = (float*)d_out;
    char*  wsb = (char*)d_ws;

    unsigned short* XNB = (unsigned short*)(wsb);
    float* ZP  = (float*)(wsb + PBASE);
    float* S2P = (float*)(wsb + PBASE + P_BYTES);
    float* S3P = (float*)(wsb + PBASE + 2u * P_BYTES);

    k_norm_x<<<dim3(BB), dim3(256), 0, stream>>>(x, XNB, out);
    k_gemm_f<<<dim3(8 * 391), dim3(256), 0, stream>>>(w, XNB, rescale, ZP, S2P, S3P);
    k_final <<<dim3(BB), dim3(256), 0, stream>>>(w, y, rescale, XNB, ZP, S2P, S3P, out);
}

// Round 5
// 149.041 us; speedup vs baseline: 1.2433x; 1.2433x over previous
//
#include <hip/hip_runtime.h>
#include <math.h>

#define BB 512
#define DD 512
#define CC 100000
#define CCPAD 100096          // 782 * 128
#define MARGIN 0.2f
#define CLIP_EPS 1e-8f
#define NCOLT 782             // class tiles of 128

typedef short short8 __attribute__((ext_vector_type(8)));
typedef float f32x4  __attribute__((ext_vector_type(4)));

// ---- workspace layout (byte offsets) ----
#define XNB_BYTES   524288u                       // bf16[512*512]
#define P_BYTES     1601536u                      // float[782*512]
#define PBASE       XNB_BYTES
#define AUX_OFF     (PBASE + 3u * P_BYTES)        // WNB bf16[100096*512]

__device__ inline unsigned short f2bf(float a) {
    unsigned u = __builtin_bit_cast(unsigned, a);
    return (unsigned short)((u + 0x7fffu + ((u >> 16) & 1u)) >> 16);
}
__device__ inline unsigned pk2(float a, float b) {
    return (unsigned)f2bf(a) | ((unsigned)f2bf(b) << 16);
}
__device__ inline float bf2f(unsigned short h) {
    unsigned u = ((unsigned)h) << 16;
    return __builtin_bit_cast(float, u);
}
// swizzled element offset within a [128][32] bf16 tile; kk multiple of 8
__device__ inline int soff(int row, int kk) {
    return row * 32 + (kk ^ (((row >> 1) & 3) << 3));
}

// ---------------- kernel 1: normalize x rows -> bf16, zero out ----------------
__global__ __launch_bounds__(256) void k_norm_x(const float* __restrict__ x,
                                                unsigned short* __restrict__ XNB,
                                                float* __restrict__ out) {
    int row = blockIdx.x, tid = threadIdx.x;
    float v0 = x[row * DD + tid];
    float v1 = x[row * DD + tid + 256];
    float ss = v0 * v0 + v1 * v1;
    for (int m = 1; m < 64; m <<= 1) ss += __shfl_xor(ss, m, 64);
    __shared__ float sm[4];
    int wid = tid >> 6, lane = tid & 63;
    if (lane == 0) sm[wid] = ss;
    __syncthreads();
    float inv = 1.0f / fmaxf(sqrtf(sm[0] + sm[1] + sm[2] + sm[3]), 1e-12f);
    XNB[row * DD + tid]       = f2bf(v0 * inv);
    XNB[row * DD + tid + 256] = f2bf(v1 * inv);
    if (row == 0 && tid == 0) out[0] = 0.0f;
}

// ------------- kernel 1b: normalized bf16 W, zero-padded rows -------------
__global__ __launch_bounds__(256) void k_wnormc(const float* __restrict__ w,
                                                unsigned short* __restrict__ WNB) {
    int wid = threadIdx.x >> 6, lane = threadIdx.x & 63;
    int row = blockIdx.x * 4 + wid;
    uint2* o0 = (uint2*)(WNB + (size_t)row * DD) + lane;
    uint2* o1 = (uint2*)(WNB + (size_t)row * DD + 256) + lane;
    if (row >= CC) {
        uint2 z = make_uint2(0u, 0u);
        *o0 = z; *o1 = z;
        return;
    }
    const float4* wr = (const float4*)(w + (size_t)row * DD);
    float4 a = wr[lane];
    float4 b = wr[lane + 64];
    float ss = a.x*a.x + a.y*a.y + a.z*a.z + a.w*a.w
             + b.x*b.x + b.y*b.y + b.z*b.z + b.w*b.w;
    for (int m = 1; m < 64; m <<= 1) ss += __shfl_xor(ss, m, 64);
    float inv = 1.0f / fmaxf(sqrtf(ss), 1e-12f);
    *o0 = make_uint2(pk2(a.x*inv, a.y*inv), pk2(a.z*inv, a.w*inv));
    *o1 = make_uint2(pk2(b.x*inv, b.y*inv), pk2(b.z*inv, b.w*inv));
}

// ---------------- kernel 2: dbuf gload_lds bf16 MFMA + fused stats ----------------
// 1D grid 3128 (XCD-chunked). 4 waves (2x2), tile 128 classes x 128 batch.
// K=512 in 16 steps of BK=32. Double-buffered LDS, global_load_lds w16 for both
// operands (per-lane pre-swizzled sources), ONE barrier per K-step: stage(k+1)
// overlaps compute(k); the barrier's vmcnt(0) drain lands after the MFMAs.
__global__ __launch_bounds__(256) void k_gemm_bf(const unsigned short* __restrict__ WNB,
                                                 const unsigned short* __restrict__ XNB,
                                                 const float* __restrict__ rescale_p,
                                                 float* __restrict__ ZP,
                                                 float* __restrict__ S2P,
                                                 float* __restrict__ S3P) {
    __shared__ __align__(16) unsigned short Wt[2][128 * 32];
    __shared__ __align__(16) unsigned short Xs[2][128 * 32];
    __shared__ float st[2][2][64][3];   // [batch half][class half][batch row][stat]

    int h = blockIdx.x;
    int logical = (h & 7) * 391 + (h >> 3);   // 3128 = 8*391, bijective
    int ct = logical >> 2;                    // class tile 0..781
    int bt = logical & 3;                     // batch tile 0..3

    int tid = threadIdx.x;
    int lane = tid & 63, wid = tid >> 6;
    int wr = wid >> 1, wc = wid & 1;          // wr: class half, wc: batch half
    float rescale = rescale_p[0];

    // staging geometry: chunk ch = i*256 + wid*64 + lane ; row = ch>>2 ; j = ch&3
    // LDS stays linear for gload_lds; SOURCE group index is inverse-swizzled.
    int rl0 = wid * 16 + (lane >> 2);         // + i*64
    int j0  = lane & 3;
    const unsigned short* wbase = WNB + (size_t)(ct * 128) * DD;
    const unsigned short* xbase = XNB + (size_t)(bt * 128) * DD;

    auto STAGE = [&](int b, int kt) {
#pragma unroll
        for (int i = 0; i < 2; ++i) {
            int rl = i * 64 + rl0;
            int jsrc = j0 ^ ((rl >> 1) & 3);
            const unsigned short* ws_ = wbase + (size_t)rl * DD + kt * 32 + jsrc * 8;
            const unsigned short* xs_ = xbase + (size_t)rl * DD + kt * 32 + jsrc * 8;
            unsigned short* wd = &Wt[b][(i * 64 + wid * 16) * 32];
            unsigned short* xd = &Xs[b][(i * 64 + wid * 16) * 32];
            __builtin_amdgcn_global_load_lds(
                (const __attribute__((address_space(1))) void*)ws_,
                (__attribute__((address_space(3))) void*)wd, 16, 0, 0);
            __builtin_amdgcn_global_load_lds(
                (const __attribute__((address_space(1))) void*)xs_,
                (__attribute__((address_space(3))) void*)xd, 16, 0, 0);
        }
    };

    // fragment read offsets (verified soff pattern, 0 conflicts)
    int ro[4], co[4];
#pragma unroll
    for (int i = 0; i < 4; i++) {
        ro[i] = soff(wr * 64 + i * 16 + (lane & 15), (lane >> 4) * 8);  // class (A)
        co[i] = soff(wc * 64 + i * 16 + (lane & 15), (lane >> 4) * 8);  // batch (B)
    }

    f32x4 acc[4][4];
#pragma unroll
    for (int i = 0; i < 4; i++)
#pragma unroll
        for (int j = 0; j < 4; j++) acc[i][j] = (f32x4){0.f, 0.f, 0.f, 0.f};

    auto COMPUTE = [&](int b) {
        short8 a[4], bb[4];
#pragma unroll
        for (int i = 0; i < 4; i++) a[i]  = *(const short8*)&Wt[b][ro[i]];
#pragma unroll
        for (int i = 0; i < 4; i++) bb[i] = *(const short8*)&Xs[b][co[i]];
#pragma unroll
        for (int i = 0; i < 4; i++)
#pragma unroll
            for (int j = 0; j < 4; j++)
                acc[i][j] = __builtin_amdgcn_mfma_f32_16x16x32_bf16(a[i], bb[j], acc[i][j], 0, 0, 0);
    };

    // prologue
    STAGE(0, 0);
    __syncthreads();                       // buf0 ready

    // main loop: 1 barrier per K-step; stage(k+1) in flight across compute(k)
    for (int kt = 0; kt < 16; ++kt) {
        if (kt < 15) STAGE((kt + 1) & 1, kt + 1);
        COMPUTE(kt & 1);
        __syncthreads();                   // drains vmcnt (next buf ready) + LDS reuse safe
    }

    // ---- epilogue: cos -> clip -> exp stats (classes in-thread) ----
    float mref = fabsf(rescale);
    const float L2E = 1.44269504f;
    float rs = rescale * L2E, mb = mref * L2E;
    float zz[4] = {0.f,0.f,0.f,0.f}, q2[4] = {0.f,0.f,0.f,0.f}, q3[4] = {0.f,0.f,0.f,0.f};
#pragma unroll
    for (int mi = 0; mi < 4; mi++) {
#pragma unroll
        for (int reg = 0; reg < 4; reg++) {
            int c = ct * 128 + wr * 64 + mi * 16 + (lane >> 4) * 4 + reg;
            float mask = (c < CC) ? 1.0f : 0.0f;
#pragma unroll
            for (int ni = 0; ni < 4; ni++) {
                float cosv = acc[mi][ni][reg];
                cosv = fminf(fmaxf(cosv, -1.0f + CLIP_EPS), 1.0f - CLIP_EPS);
                float e = exp2f(fmaf(cosv, rs, -mb)) * mask;
                float e2 = e * e;
                zz[ni] += e;
                q2[ni] += e2;
                q3[ni] = fmaf(e2, e, q3[ni]);
            }
        }
    }
#pragma unroll
    for (int msk = 16; msk < 64; msk <<= 1) {
#pragma unroll
        for (int ni = 0; ni < 4; ni++) {
            zz[ni] += __shfl_xor(zz[ni], msk, 64);
            q2[ni] += __shfl_xor(q2[ni], msk, 64);
            q3[ni] += __shfl_xor(q3[ni], msk, 64);
        }
    }
    if (lane < 16) {
#pragma unroll
        for (int ni = 0; ni < 4; ni++) {
            st[wc][wr][ni * 16 + lane][0] = zz[ni];
            st[wc][wr][ni * 16 + lane][1] = q2[ni];
            st[wc][wr][ni * 16 + lane][2] = q3[ni];
        }
    }
    __syncthreads();
    if (tid < 128) {
        int bh = tid >> 6, bl = tid & 63;
        float Z  = st[bh][0][bl][0] + st[bh][1][bl][0];
        float S2 = st[bh][0][bl][1] + st[bh][1][bl][1];
        float S3 = st[bh][0][bl][2] + st[bh][1][bl][2];
        size_t gi = (size_t)ct * BB + bt * 128 + tid;
        ZP[gi] = Z; S2P[gi] = S2; S3P[gi] = S3;
    }
}

// ---------------- kernel 3: combine partials, margin fixup, loss ----------------
__global__ __launch_bounds__(256) void k_final(const float* __restrict__ w,
                                               const int* __restrict__ y,
                                               const float* __restrict__ rescale_p,
                                               const unsigned short* __restrict__ XNB,
                                               const float* __restrict__ ZP,
                                               const float* __restrict__ S2P,
                                               const float* __restrict__ S3P,
                                               float* __restrict__ out) {
    int b = blockIdx.x, tid = threadIdx.x;
    int yb = y[b];

    float d0 = 0.f, q0 = 0.f;
#pragma unroll
    for (int i = 0; i < 2; i++) {
        int idx = tid + i * 256;
        float xv = bf2f(XNB[b * DD + idx]);
        float wvv = w[(size_t)yb * DD + idx];
        d0 = fmaf(xv, wvv, d0);
        q0 = fmaf(wvv, wvv, q0);
    }
    for (int m = 1; m < 64; m <<= 1) { d0 += __shfl_xor(d0, m, 64); q0 += __shfl_xor(q0, m, 64); }
    __shared__ float sd[4], sq[4], szs[4], s2s[4], s3s[4];
    int wid = tid >> 6, lane = tid & 63;
    if (lane == 0) { sd[wid] = d0; sq[wid] = q0; }

    float rz = 0.f, r2 = 0.f, r3 = 0.f;
    for (int ch = tid; ch < NCOLT; ch += 256) {
        size_t gi = (size_t)ch * BB + b;
        rz += ZP[gi]; r2 += S2P[gi]; r3 += S3P[gi];
    }
    for (int m = 1; m < 64; m <<= 1) {
        rz += __shfl_xor(rz, m, 64);
        r2 += __shfl_xor(r2, m, 64);
        r3 += __shfl_xor(r3, m, 64);
    }
    if (lane == 0) { szs[wid] = rz; s2s[wid] = r2; s3s[wid] = r3; }
    __syncthreads();

    if (tid == 0) {
        float Z  = szs[0] + szs[1] + szs[2] + szs[3];
        float S2 = s2s[0] + s2s[1] + s2s[2] + s2s[3];
        float S3 = s3s[0] + s3s[1] + s3s[2] + s3s[3];
        float dot = sd[0] + sd[1] + sd[2] + sd[3];
        float ssq = sq[0] + sq[1] + sq[2] + sq[3];
        float rescale = rescale_p[0];
        float mref = fabsf(rescale);
        float winv = 1.0f / fmaxf(sqrtf(ssq), 1e-12f);
        float fc = fminf(fmaxf(dot * winv, -1.0f + CLIP_EPS), 1.0f - CLIP_EPS);
        float su = rescale * fc;
        float fcm = fc * cosf(MARGIN) - sqrtf(fmaxf(1.0f - fc * fc, 0.0f)) * sinf(MARGIN);
        float smv = rescale * fcm;
        float eU = __expf(su - mref), eM = __expf(smv - mref);
        Z  += eM - eU;
        S2 += eM * eM - eU * eU;
        S3 += eM * eM * eM - eU * eU * eU;
        float py = eM / Z;
        float sumexp = (float)CC + 1.0f + S2 / (2.0f * Z * Z) + S3 / (6.0f * Z * Z * Z);
        float nll = logf(sumexp) - py;
        atomicAdd(out, nll * (1.0f / (float)BB));
    }
}

extern "C" void kernel_launch(void* const* d_in, const int* in_sizes, int n_in,
                              void* d_out, int out_size, void* d_ws, size_t ws_size,
                              hipStream_t stream) {
    const float* x       = (const float*)d_in[0];
    const int*   y       = (const int*)  d_in[1];
    const float* w       = (const float*)d_in[2];
    const float* rescale = (const float*)d_in[3];
    float* out = (float*)d_out;
    char*  wsb = (char*)d_ws;

    unsigned short* XNB = (unsigned short*)(wsb);
    float* ZP  = (float*)(wsb + PBASE);
    float* S2P = (float*)(wsb + PBASE + P_BYTES);
    float* S3P = (float*)(wsb + PBASE + 2u * P_BYTES);
    unsigned short* WNB = (unsigned short*)(wsb + AUX_OFF);

    k_norm_x <<<dim3(BB), dim3(256), 0, stream>>>(x, XNB, out);
    k_wnormc <<<dim3(CCPAD / 4), dim3(256), 0, stream>>>(w, WNB);
    k_gemm_bf<<<dim3(8 * 391), dim3(256), 0, stream>>>(WNB, XNB, rescale, ZP, S2P, S3P);
    k_final  <<<dim3(BB), dim3(256), 0, stream>>>(w, y, rescale, XNB, ZP, S2P, S3P, out);
}

// Round 6
// 143.839 us; speedup vs baseline: 1.2883x; 1.0362x over previous
//
#include <hip/hip_runtime.h>
#include <math.h>

#define BB 512
#define DD 512
#define CC 100000
#define CCPAD 100096          // 782 * 128
#define MARGIN 0.2f
#define CLIP_EPS 1e-8f
#define NCOLT 782             // class tiles of 128

typedef short short8 __attribute__((ext_vector_type(8)));
typedef float f32x4  __attribute__((ext_vector_type(4)));

// ---- workspace layout (byte offsets) ----
#define XNB_BYTES   524288u                       // bf16[512*512]
#define P_BYTES     1601536u                      // float[782*512]
#define PBASE       XNB_BYTES
#define AUX_OFF     (PBASE + 3u * P_BYTES)        // WNB bf16[100096*512]

__device__ inline unsigned short f2bf(float a) {
    unsigned u = __builtin_bit_cast(unsigned, a);
    return (unsigned short)((u + 0x7fffu + ((u >> 16) & 1u)) >> 16);
}
__device__ inline unsigned pk2(float a, float b) {
    return (unsigned)f2bf(a) | ((unsigned)f2bf(b) << 16);
}
__device__ inline float bf2f(unsigned short h) {
    unsigned u = ((unsigned)h) << 16;
    return __builtin_bit_cast(float, u);
}
// swizzled element offset within a [128][32] bf16 tile; kk multiple of 8
__device__ inline int soff(int row, int kk) {
    return row * 32 + (kk ^ (((row >> 1) & 3) << 3));
}

// ---------------- kernel 1: normalize x rows -> bf16, zero out ----------------
__global__ __launch_bounds__(256) void k_norm_x(const float* __restrict__ x,
                                                unsigned short* __restrict__ XNB,
                                                float* __restrict__ out) {
    int row = blockIdx.x, tid = threadIdx.x;
    float v0 = x[row * DD + tid];
    float v1 = x[row * DD + tid + 256];
    float ss = v0 * v0 + v1 * v1;
    for (int m = 1; m < 64; m <<= 1) ss += __shfl_xor(ss, m, 64);
    __shared__ float sm[4];
    int wid = tid >> 6, lane = tid & 63;
    if (lane == 0) sm[wid] = ss;
    __syncthreads();
    float inv = 1.0f / fmaxf(sqrtf(sm[0] + sm[1] + sm[2] + sm[3]), 1e-12f);
    XNB[row * DD + tid]       = f2bf(v0 * inv);
    XNB[row * DD + tid + 256] = f2bf(v1 * inv);
    if (row == 0 && tid == 0) out[0] = 0.0f;
}

// ------------- kernel 1b: normalized bf16 W, zero-padded rows -------------
__global__ __launch_bounds__(256) void k_wnormc(const float* __restrict__ w,
                                                unsigned short* __restrict__ WNB) {
    int wid = threadIdx.x >> 6, lane = threadIdx.x & 63;
    int row = blockIdx.x * 4 + wid;
    uint2* o0 = (uint2*)(WNB + (size_t)row * DD) + lane;
    uint2* o1 = (uint2*)(WNB + (size_t)row * DD + 256) + lane;
    if (row >= CC) {
        uint2 z = make_uint2(0u, 0u);
        *o0 = z; *o1 = z;
        return;
    }
    const float4* wr = (const float4*)(w + (size_t)row * DD);
    float4 a = wr[lane];
    float4 b = wr[lane + 64];
    float ss = a.x*a.x + a.y*a.y + a.z*a.z + a.w*a.w
             + b.x*b.x + b.y*b.y + b.z*b.z + b.w*b.w;
    for (int m = 1; m < 64; m <<= 1) ss += __shfl_xor(ss, m, 64);
    float inv = 1.0f / fmaxf(sqrtf(ss), 1e-12f);
    *o0 = make_uint2(pk2(a.x*inv, a.y*inv), pk2(a.z*inv, a.w*inv));
    *o1 = make_uint2(pk2(b.x*inv, b.y*inv), pk2(b.z*inv, b.w*inv));
}

// ------- kernel 2: triple-buffered counted-vmcnt bf16 MFMA + fused stats -------
// 1D grid 3128 (XCD-chunked). 4 waves (2x2), tile 128 classes x 128 batch.
// K=512 in 16 steps of BK=32. THREE LDS buffers, prefetch distance 3,
// raw s_barrier + literal s_waitcnt vmcnt(8/4/0) -- loads stay in flight
// across barriers (T4); no vmcnt(0) drain in the main loop.
__global__ __launch_bounds__(256) void k_gemm_bf(const unsigned short* __restrict__ WNB,
                                                 const unsigned short* __restrict__ XNB,
                                                 const float* __restrict__ rescale_p,
                                                 float* __restrict__ ZP,
                                                 float* __restrict__ S2P,
                                                 float* __restrict__ S3P) {
    __shared__ __align__(16) unsigned short Wt[3][128 * 32];
    __shared__ __align__(16) unsigned short Xs[3][128 * 32];
    __shared__ float st[2][2][64][3];   // [batch half][class half][batch row][stat]

    int h = blockIdx.x;
    int logical = (h & 7) * 391 + (h >> 3);   // 3128 = 8*391, bijective
    int ct = logical >> 2;                    // class tile 0..781
    int bt = logical & 3;                     // batch tile 0..3

    int tid = threadIdx.x;
    int lane = tid & 63, wid = tid >> 6;
    int wr = wid >> 1, wc = wid & 1;          // wr: class half, wc: batch half
    float rescale = rescale_p[0];

    // staging geometry: chunk ch = i*256 + wid*64 + lane ; row = ch>>2 ; j = ch&3
    // LDS stays linear for gload_lds; SOURCE group index is inverse-swizzled.
    int rl0 = wid * 16 + (lane >> 2);         // + i*64
    int j0  = lane & 3;
    const unsigned short* wbase = WNB + (size_t)(ct * 128) * DD;
    const unsigned short* xbase = XNB + (size_t)(bt * 128) * DD;

    auto STAGE = [&](int b, int kt) {
#pragma unroll
        for (int i = 0; i < 2; ++i) {
            int rl = i * 64 + rl0;
            int jsrc = j0 ^ ((rl >> 1) & 3);
            const unsigned short* ws_ = wbase + (size_t)rl * DD + kt * 32 + jsrc * 8;
            const unsigned short* xs_ = xbase + (size_t)rl * DD + kt * 32 + jsrc * 8;
            unsigned short* wd = &Wt[b][(i * 64 + wid * 16) * 32];
            unsigned short* xd = &Xs[b][(i * 64 + wid * 16) * 32];
            __builtin_amdgcn_global_load_lds(
                (const __attribute__((address_space(1))) void*)ws_,
                (__attribute__((address_space(3))) void*)wd, 16, 0, 0);
            __builtin_amdgcn_global_load_lds(
                (const __attribute__((address_space(1))) void*)xs_,
                (__attribute__((address_space(3))) void*)xd, 16, 0, 0);
        }
    };

    // fragment read offsets (verified soff pattern, 0 conflicts)
    int ro[4], co[4];
#pragma unroll
    for (int i = 0; i < 4; i++) {
        ro[i] = soff(wr * 64 + i * 16 + (lane & 15), (lane >> 4) * 8);  // class (A)
        co[i] = soff(wc * 64 + i * 16 + (lane & 15), (lane >> 4) * 8);  // batch (B)
    }

    f32x4 acc[4][4];
#pragma unroll
    for (int i = 0; i < 4; i++)
#pragma unroll
        for (int j = 0; j < 4; j++) acc[i][j] = (f32x4){0.f, 0.f, 0.f, 0.f};

    auto COMPUTE = [&](int b) {
        short8 a[4], bb[4];
#pragma unroll
        for (int i = 0; i < 4; i++) a[i]  = *(const short8*)&Wt[b][ro[i]];
#pragma unroll
        for (int i = 0; i < 4; i++) bb[i] = *(const short8*)&Xs[b][co[i]];
#pragma unroll
        for (int i = 0; i < 4; i++)
#pragma unroll
            for (int j = 0; j < 4; j++)
                acc[i][j] = __builtin_amdgcn_mfma_f32_16x16x32_bf16(a[i], bb[j], acc[i][j], 0, 0, 0);
    };

    // ---- prologue: fill 3 buffers, wait only for buf0 (8 newer stay in flight) ----
    STAGE(0, 0);
    STAGE(1, 1);
    STAGE(2, 2);
    asm volatile("s_waitcnt vmcnt(8)" ::: "memory");
    __builtin_amdgcn_s_barrier();          // everyone's tile-0 quarters arrived

    // ---- main loop: counted vmcnt, no full drain ----
    int cur = 0;
    for (int kt = 0; kt < 16; ++kt) {
        COMPUTE(cur);
        if (kt == 15) break;
        __builtin_amdgcn_s_barrier();      // all waves done reading buf `cur`
        if (kt < 13) {
            STAGE(cur, kt + 3);            // restage just-freed buffer
            asm volatile("s_waitcnt vmcnt(8)" ::: "memory");   // tile kt+1 arrived
        } else if (kt == 13) {
            asm volatile("s_waitcnt vmcnt(4)" ::: "memory");
        } else {
            asm volatile("s_waitcnt vmcnt(0)" ::: "memory");
        }
        __builtin_amdgcn_s_barrier();      // all waves' kt+1 data present
        cur = (cur == 2) ? 0 : cur + 1;
    }

    // ---- epilogue: cos -> clip -> exp stats (classes in-thread) ----
    float mref = fabsf(rescale);
    const float L2E = 1.44269504f;
    float rs = rescale * L2E, mb = mref * L2E;
    float zz[4] = {0.f,0.f,0.f,0.f}, q2[4] = {0.f,0.f,0.f,0.f}, q3[4] = {0.f,0.f,0.f,0.f};
#pragma unroll
    for (int mi = 0; mi < 4; mi++) {
#pragma unroll
        for (int reg = 0; reg < 4; reg++) {
            int c = ct * 128 + wr * 64 + mi * 16 + (lane >> 4) * 4 + reg;
            float mask = (c < CC) ? 1.0f : 0.0f;
#pragma unroll
            for (int ni = 0; ni < 4; ni++) {
                float cosv = acc[mi][ni][reg];
                cosv = fminf(fmaxf(cosv, -1.0f + CLIP_EPS), 1.0f - CLIP_EPS);
                float e = exp2f(fmaf(cosv, rs, -mb)) * mask;
                float e2 = e * e;
                zz[ni] += e;
                q2[ni] += e2;
                q3[ni] = fmaf(e2, e, q3[ni]);
            }
        }
    }
#pragma unroll
    for (int msk = 16; msk < 64; msk <<= 1) {
#pragma unroll
        for (int ni = 0; ni < 4; ni++) {
            zz[ni] += __shfl_xor(zz[ni], msk, 64);
            q2[ni] += __shfl_xor(q2[ni], msk, 64);
            q3[ni] += __shfl_xor(q3[ni], msk, 64);
        }
    }
    if (lane < 16) {
#pragma unroll
        for (int ni = 0; ni < 4; ni++) {
            st[wc][wr][ni * 16 + lane][0] = zz[ni];
            st[wc][wr][ni * 16 + lane][1] = q2[ni];
            st[wc][wr][ni * 16 + lane][2] = q3[ni];
        }
    }
    __syncthreads();
    if (tid < 128) {
        int bh = tid >> 6, bl = tid & 63;
        float Z  = st[bh][0][bl][0] + st[bh][1][bl][0];
        float S2 = st[bh][0][bl][1] + st[bh][1][bl][1];
        float S3 = st[bh][0][bl][2] + st[bh][1][bl][2];
        size_t gi = (size_t)ct * BB + bt * 128 + tid;
        ZP[gi] = Z; S2P[gi] = S2; S3P[gi] = S3;
    }
}

// ---------------- kernel 3: combine partials, margin fixup, loss ----------------
__global__ __launch_bounds__(256) void k_final(const float* __restrict__ w,
                                               const int* __restrict__ y,
                                               const float* __restrict__ rescale_p,
                                               const unsigned short* __restrict__ XNB,
                                               const float* __restrict__ ZP,
                                               const float* __restrict__ S2P,
                                               const float* __restrict__ S3P,
                                               float* __restrict__ out) {
    int b = blockIdx.x, tid = threadIdx.x;
    int yb = y[b];

    float d0 = 0.f, q0 = 0.f;
#pragma unroll
    for (int i = 0; i < 2; i++) {
        int idx = tid + i * 256;
        float xv = bf2f(XNB[b * DD + idx]);
        float wvv = w[(size_t)yb * DD + idx];
        d0 = fmaf(xv, wvv, d0);
        q0 = fmaf(wvv, wvv, q0);
    }
    for (int m = 1; m < 64; m <<= 1) { d0 += __shfl_xor(d0, m, 64); q0 += __shfl_xor(q0, m, 64); }
    __shared__ float sd[4], sq[4], szs[4], s2s[4], s3s[4];
    int wid = tid >> 6, lane = tid & 63;
    if (lane == 0) { sd[wid] = d0; sq[wid] = q0; }

    float rz = 0.f, r2 = 0.f, r3 = 0.f;
    for (int ch = tid; ch < NCOLT; ch += 256) {
        size_t gi = (size_t)ch * BB + b;
        rz += ZP[gi]; r2 += S2P[gi]; r3 += S3P[gi];
    }
    for (int m = 1; m < 64; m <<= 1) {
        rz += __shfl_xor(rz, m, 64);
        r2 += __shfl_xor(r2, m, 64);
        r3 += __shfl_xor(r3, m, 64);
    }
    if (lane == 0) { szs[wid] = rz; s2s[wid] = r2; s3s[wid] = r3; }
    __syncthreads();

    if (tid == 0) {
        float Z  = szs[0] + szs[1] + szs[2] + szs[3];
        float S2 = s2s[0] + s2s[1] + s2s[2] + s2s[3];
        float S3 = s3s[0] + s3s[1] + s3s[2] + s3s[3];
        float dot = sd[0] + sd[1] + sd[2] + sd[3];
        float ssq = sq[0] + sq[1] + sq[2] + sq[3];
        float rescale = rescale_p[0];
        float mref = fabsf(rescale);
        float winv = 1.0f / fmaxf(sqrtf(ssq), 1e-12f);
        float fc = fminf(fmaxf(dot * winv, -1.0f + CLIP_EPS), 1.0f - CLIP_EPS);
        float su = rescale * fc;
        float fcm = fc * cosf(MARGIN) - sqrtf(fmaxf(1.0f - fc * fc, 0.0f)) * sinf(MARGIN);
        float smv = rescale * fcm;
        float eU = __expf(su - mref), eM = __expf(smv - mref);
        Z  += eM - eU;
        S2 += eM * eM - eU * eU;
        S3 += eM * eM * eM - eU * eU * eU;
        float py = eM / Z;
        float sumexp = (float)CC + 1.0f + S2 / (2.0f * Z * Z) + S3 / (6.0f * Z * Z * Z);
        float nll = logf(sumexp) - py;
        atomicAdd(out, nll * (1.0f / (float)BB));
    }
}

extern "C" void kernel_launch(void* const* d_in, const int* in_sizes, int n_in,
                              void* d_out, int out_size, void* d_ws, size_t ws_size,
                              hipStream_t stream) {
    const float* x       = (const float*)d_in[0];
    const int*   y       = (const int*)  d_in[1];
    const float* w       = (const float*)d_in[2];
    const float* rescale = (const float*)d_in[3];
    float* out = (float*)d_out;
    char*  wsb = (char*)d_ws;

    unsigned short* XNB = (unsigned short*)(wsb);
    float* ZP  = (float*)(wsb + PBASE);
    float* S2P = (float*)(wsb + PBASE + P_BYTES);
    float* S3P = (float*)(wsb + PBASE + 2u * P_BYTES);
    unsigned short* WNB = (unsigned short*)(wsb + AUX_OFF);

    k_norm_x <<<dim3(BB), dim3(256), 0, stream>>>(x, XNB, out);
    k_wnormc <<<dim3(CCPAD / 4), dim3(256), 0, stream>>>(w, WNB);
    k_gemm_bf<<<dim3(8 * 391), dim3(256), 0, stream>>>(WNB, XNB, rescale, ZP, S2P, S3P);
    k_final  <<<dim3(BB), dim3(256), 0, stream>>>(w, y, rescale, XNB, ZP, S2P, S3P, out);
}

// Round 7
// 112.019 us; speedup vs baseline: 1.6542x; 1.2841x over previous
//
#include <hip/hip_runtime.h>
#include <math.h>

#define BB 512
#define DD 512
#define CC 100000
#define CCPAD 100096          // 782 * 128
#define MARGIN 0.2f
#define CLIP_EPS 1e-8f
#define NCOLT 782             // class tiles of 128

typedef float f32x4  __attribute__((ext_vector_type(4)));

// ---- workspace layout (byte offsets) ----
#define XN8_BYTES   262144u                       // fp8[512*512]
#define P_BYTES     1601536u                      // float[782*512]
#define PBASE       XN8_BYTES
#define AUX_OFF     (PBASE + 3u * P_BYTES)        // WN8 fp8[100096*512] = 51.2 MB

// ---- OCP e4m3fn encode with RNE (|a| <= 1 guaranteed by normalization) ----
__device__ inline unsigned f2e4m3(float a) {
    unsigned u = __builtin_bit_cast(unsigned, a);
    unsigned s = (u >> 24) & 0x80u;
    float ab = fabsf(a);
    unsigned code;
    if (ab >= 0.015625f) {   // normal: exp >= -6 (no overflow possible, |a|<=1)
        unsigned r = (u & 0x7FFFFFFFu) + 0x7FFFFu + ((u >> 20) & 1u);  // RNE @ 3 mant bits
        int e = (int)(r >> 23) - 127;
        unsigned m = (r >> 20) & 7u;
        code = (unsigned)((e + 7) << 3) | m;
    } else {                 // subnormal: value = n * 2^-9, n in [0,8] (8 -> normal 2^-6)
        code = (unsigned)rintf(ab * 512.0f);
    }
    return s | code;
}

// swizzled byte offset within a [128 rows][64 B] fp8 tile; b = byte-in-row
// (16B-granule XOR involution; conflict-free b64 frag reads, gload_lds-compatible)
__device__ inline int soff8(int row, int b) {
    return row * 64 + ((((b >> 4) ^ ((row >> 1) & 3)) << 4)) + (b & 15);
}

// ---------------- kernel 1: normalize x rows -> fp8, zero out ----------------
__global__ __launch_bounds__(256) void k_norm_x(const float* __restrict__ x,
                                                unsigned char* __restrict__ XN8,
                                                float* __restrict__ out) {
    int row = blockIdx.x, tid = threadIdx.x;
    float2 v = *(const float2*)(x + row * DD + tid * 2);
    float ss = v.x * v.x + v.y * v.y;
    for (int m = 1; m < 64; m <<= 1) ss += __shfl_xor(ss, m, 64);
    __shared__ float sm[4];
    int wid = tid >> 6, lane = tid & 63;
    if (lane == 0) sm[wid] = ss;
    __syncthreads();
    float inv = 1.0f / fmaxf(sqrtf(sm[0] + sm[1] + sm[2] + sm[3]), 1e-12f);
    unsigned c0 = f2e4m3(v.x * inv), c1 = f2e4m3(v.y * inv);
    *(unsigned short*)(XN8 + row * DD + tid * 2) = (unsigned short)(c0 | (c1 << 8));
    if (row == 0 && tid == 0) out[0] = 0.0f;
}

// ------------- kernel 1b: normalized fp8 W, zero-padded rows -------------
__global__ __launch_bounds__(256) void k_wnormc(const float* __restrict__ w,
                                                unsigned char* __restrict__ WN8) {
    int wid = threadIdx.x >> 6, lane = threadIdx.x & 63;
    int row = blockIdx.x * 4 + wid;
    unsigned* o0 = (unsigned*)(WN8 + (size_t)row * DD + 4 * lane);
    unsigned* o1 = (unsigned*)(WN8 + (size_t)row * DD + 256 + 4 * lane);
    if (row >= CC) { *o0 = 0u; *o1 = 0u; return; }
    const float4* wr = (const float4*)(w + (size_t)row * DD);
    float4 a = wr[lane];
    float4 b = wr[lane + 64];
    float ss = a.x*a.x + a.y*a.y + a.z*a.z + a.w*a.w
             + b.x*b.x + b.y*b.y + b.z*b.z + b.w*b.w;
    for (int m = 1; m < 64; m <<= 1) ss += __shfl_xor(ss, m, 64);
    float inv = 1.0f / fmaxf(sqrtf(ss), 1e-12f);
    *o0 = f2e4m3(a.x*inv) | (f2e4m3(a.y*inv) << 8) | (f2e4m3(a.z*inv) << 16) | (f2e4m3(a.w*inv) << 24);
    *o1 = f2e4m3(b.x*inv) | (f2e4m3(b.y*inv) << 8) | (f2e4m3(b.z*inv) << 16) | (f2e4m3(b.w*inv) << 24);
}

// ------- kernel 2: fp8 triple-buffered counted-vmcnt MFMA + fused stats -------
// 1D grid 3128 (XCD-chunked). 4 waves (2x2), tile 128 classes x 128 batch.
// K=512 in 8 steps of BK=64. Three LDS buffers, prefetch distance 3,
// s_barrier + literal vmcnt(8/4/0) -- same verified schedule as r6 (4 loads/stage).
__global__ __launch_bounds__(256) void k_gemm8(const unsigned char* __restrict__ WN8,
                                               const unsigned char* __restrict__ XN8,
                                               const float* __restrict__ rescale_p,
                                               float* __restrict__ ZP,
                                               float* __restrict__ S2P,
                                               float* __restrict__ S3P) {
    __shared__ __align__(16) unsigned char Wt[3][128 * 64];
    __shared__ __align__(16) unsigned char Xs[3][128 * 64];
    __shared__ float st[2][2][64][3];   // [batch half][class half][batch row][stat]

    int h = blockIdx.x;
    int logical = (h & 7) * 391 + (h >> 3);   // 3128 = 8*391, bijective
    int ct = logical >> 2;                    // class tile 0..781
    int bt = logical & 3;                     // batch tile 0..3

    int tid = threadIdx.x;
    int lane = tid & 63, wid = tid >> 6;
    int wr = wid >> 1, wc = wid & 1;          // wr: class half, wc: batch half
    float rescale = rescale_p[0];

    // staging: chunk ch = i*256 + wid*64 + lane ; row = ch>>2 ; granule j = ch&3
    // LDS linear for gload_lds; SOURCE granule is inverse-swizzled (involution).
    int rl0 = wid * 16 + (lane >> 2);
    int j0  = lane & 3;
    const unsigned char* wbase = WN8 + (size_t)(ct * 128) * DD;
    const unsigned char* xbase = XN8 + (size_t)(bt * 128) * DD;

    auto STAGE = [&](int b, int kt) {
#pragma unroll
        for (int i = 0; i < 2; ++i) {
            int rl = i * 64 + rl0;
            int jsrc = j0 ^ ((rl >> 1) & 3);
            const unsigned char* ws_ = wbase + (size_t)rl * DD + kt * 64 + jsrc * 16;
            const unsigned char* xs_ = xbase + (size_t)rl * DD + kt * 64 + jsrc * 16;
            unsigned char* wd = &Wt[b][(i * 256 + wid * 64) * 16];
            unsigned char* xd = &Xs[b][(i * 256 + wid * 64) * 16];
            __builtin_amdgcn_global_load_lds(
                (const __attribute__((address_space(1))) void*)ws_,
                (__attribute__((address_space(3))) void*)wd, 16, 0, 0);
            __builtin_amdgcn_global_load_lds(
                (const __attribute__((address_space(1))) void*)xs_,
                (__attribute__((address_space(3))) void*)xd, 16, 0, 0);
        }
    };

    // fragment byte offsets: slice sl (k0 = sl*32), frag tile i
    int roA[2][4], roB[2][4];
#pragma unroll
    for (int sl = 0; sl < 2; ++sl)
#pragma unroll
        for (int i = 0; i < 4; ++i) {
            int bb = sl * 32 + (lane >> 4) * 8;
            roA[sl][i] = soff8(wr * 64 + i * 16 + (lane & 15), bb);
            roB[sl][i] = soff8(wc * 64 + i * 16 + (lane & 15), bb);
        }

    f32x4 acc[4][4];
#pragma unroll
    for (int i = 0; i < 4; i++)
#pragma unroll
        for (int j = 0; j < 4; j++) acc[i][j] = (f32x4){0.f, 0.f, 0.f, 0.f};

    auto COMPUTE = [&](int b) {
#pragma unroll
        for (int sl = 0; sl < 2; ++sl) {
            long a[4], bb[4];
#pragma unroll
            for (int i = 0; i < 4; i++) a[i]  = *(const long*)&Wt[b][roA[sl][i]];
#pragma unroll
            for (int i = 0; i < 4; i++) bb[i] = *(const long*)&Xs[b][roB[sl][i]];
#pragma unroll
            for (int i = 0; i < 4; i++)
#pragma unroll
                for (int j = 0; j < 4; j++)
                    acc[i][j] = __builtin_amdgcn_mfma_f32_16x16x32_fp8_fp8(a[i], bb[j], acc[i][j], 0, 0, 0);
        }
    };

    // ---- prologue: fill 3 buffers, wait only for buf0 (8 newer stay in flight) ----
    STAGE(0, 0);
    STAGE(1, 1);
    STAGE(2, 2);
    asm volatile("s_waitcnt vmcnt(8)" ::: "memory");
    __builtin_amdgcn_s_barrier();

    // ---- main loop: counted vmcnt, no full drain ----
    int cur = 0;
    for (int kt = 0; kt < 8; ++kt) {
        COMPUTE(cur);
        if (kt == 7) break;
        __builtin_amdgcn_s_barrier();      // all waves done reading buf `cur`
        if (kt < 5) {
            STAGE(cur, kt + 3);            // restage just-freed buffer
            asm volatile("s_waitcnt vmcnt(8)" ::: "memory");   // tile kt+1 arrived
        } else if (kt == 5) {
            asm volatile("s_waitcnt vmcnt(4)" ::: "memory");
        } else {
            asm volatile("s_waitcnt vmcnt(0)" ::: "memory");
        }
        __builtin_amdgcn_s_barrier();      // all waves' kt+1 data present
        cur = (cur == 2) ? 0 : cur + 1;
    }

    // ---- epilogue: cos -> clip -> exp stats (classes in-thread) ----
    float mref = fabsf(rescale);
    const float L2E = 1.44269504f;
    float rs = rescale * L2E, mb = mref * L2E;
    float zz[4] = {0.f,0.f,0.f,0.f}, q2[4] = {0.f,0.f,0.f,0.f}, q3[4] = {0.f,0.f,0.f,0.f};
#pragma unroll
    for (int mi = 0; mi < 4; mi++) {
#pragma unroll
        for (int reg = 0; reg < 4; reg++) {
            int c = ct * 128 + wr * 64 + mi * 16 + (lane >> 4) * 4 + reg;
            float mask = (c < CC) ? 1.0f : 0.0f;
#pragma unroll
            for (int ni = 0; ni < 4; ni++) {
                float cosv = acc[mi][ni][reg];
                cosv = fminf(fmaxf(cosv, -1.0f + CLIP_EPS), 1.0f - CLIP_EPS);
                float e = exp2f(fmaf(cosv, rs, -mb)) * mask;
                float e2 = e * e;
                zz[ni] += e;
                q2[ni] += e2;
                q3[ni] = fmaf(e2, e, q3[ni]);
            }
        }
    }
#pragma unroll
    for (int msk = 16; msk < 64; msk <<= 1) {
#pragma unroll
        for (int ni = 0; ni < 4; ni++) {
            zz[ni] += __shfl_xor(zz[ni], msk, 64);
            q2[ni] += __shfl_xor(q2[ni], msk, 64);
            q3[ni] += __shfl_xor(q3[ni], msk, 64);
        }
    }
    if (lane < 16) {
#pragma unroll
        for (int ni = 0; ni < 4; ni++) {
            st[wc][wr][ni * 16 + lane][0] = zz[ni];
            st[wc][wr][ni * 16 + lane][1] = q2[ni];
            st[wc][wr][ni * 16 + lane][2] = q3[ni];
        }
    }
    __syncthreads();
    if (tid < 128) {
        int bh = tid >> 6, bl = tid & 63;
        float Z  = st[bh][0][bl][0] + st[bh][1][bl][0];
        float S2 = st[bh][0][bl][1] + st[bh][1][bl][1];
        float S3 = st[bh][0][bl][2] + st[bh][1][bl][2];
        size_t gi = (size_t)ct * BB + bt * 128 + tid;
        ZP[gi] = Z; S2P[gi] = S2; S3P[gi] = S3;
    }
}

// ---------------- kernel 3: combine partials, margin fixup, loss ----------------
__global__ __launch_bounds__(256) void k_final(const float* __restrict__ x,
                                               const float* __restrict__ w,
                                               const int* __restrict__ y,
                                               const float* __restrict__ rescale_p,
                                               const float* __restrict__ ZP,
                                               const float* __restrict__ S2P,
                                               const float* __restrict__ S3P,
                                               float* __restrict__ out) {
    int b = blockIdx.x, tid = threadIdx.x;
    int yb = y[b];

    // dot(x_b, w_yb), ||x_b||^2, ||w_yb||^2 in f32
    float dq = 0.f, qx = 0.f, qw = 0.f;
#pragma unroll
    for (int i = 0; i < 2; i++) {
        int idx = tid + i * 256;
        float xv = x[b * DD + idx];
        float wv = w[(size_t)yb * DD + idx];
        dq = fmaf(xv, wv, dq);
        qx = fmaf(xv, xv, qx);
        qw = fmaf(wv, wv, qw);
    }
    for (int m = 1; m < 64; m <<= 1) {
        dq += __shfl_xor(dq, m, 64);
        qx += __shfl_xor(qx, m, 64);
        qw += __shfl_xor(qw, m, 64);
    }
    __shared__ float sd[4], sx[4], sw[4], szs[4], s2s[4], s3s[4];
    int wid = tid >> 6, lane = tid & 63;
    if (lane == 0) { sd[wid] = dq; sx[wid] = qx; sw[wid] = qw; }

    float rz = 0.f, r2 = 0.f, r3 = 0.f;
    for (int ch = tid; ch < NCOLT; ch += 256) {
        size_t gi = (size_t)ch * BB + b;
        rz += ZP[gi]; r2 += S2P[gi]; r3 += S3P[gi];
    }
    for (int m = 1; m < 64; m <<= 1) {
        rz += __shfl_xor(rz, m, 64);
        r2 += __shfl_xor(r2, m, 64);
        r3 += __shfl_xor(r3, m, 64);
    }
    if (lane == 0) { szs[wid] = rz; s2s[wid] = r2; s3s[wid] = r3; }
    __syncthreads();

    if (tid == 0) {
        float Z  = szs[0] + szs[1] + szs[2] + szs[3];
        float S2 = s2s[0] + s2s[1] + s2s[2] + s2s[3];
        float S3 = s3s[0] + s3s[1] + s3s[2] + s3s[3];
        float dot = sd[0] + sd[1] + sd[2] + sd[3];
        float ssx = sx[0] + sx[1] + sx[2] + sx[3];
        float ssw = sw[0] + sw[1] + sw[2] + sw[3];
        float rescale = rescale_p[0];
        float mref = fabsf(rescale);
        float fc = dot / (fmaxf(sqrtf(ssx), 1e-12f) * fmaxf(sqrtf(ssw), 1e-12f));
        fc = fminf(fmaxf(fc, -1.0f + CLIP_EPS), 1.0f - CLIP_EPS);
        float su = rescale * fc;
        float fcm = fc * cosf(MARGIN) - sqrtf(fmaxf(1.0f - fc * fc, 0.0f)) * sinf(MARGIN);
        float smv = rescale * fcm;
        float eU = __expf(su - mref), eM = __expf(smv - mref);
        Z  += eM - eU;
        S2 += eM * eM - eU * eU;
        S3 += eM * eM * eM - eU * eU * eU;
        float py = eM / Z;
        // sum_c exp(p_c) = C + 1 + S2/(2Z^2) + S3/(6Z^3) (remainder < 1e-13)
        float sumexp = (float)CC + 1.0f + S2 / (2.0f * Z * Z) + S3 / (6.0f * Z * Z * Z);
        float nll = logf(sumexp) - py;
        atomicAdd(out, nll * (1.0f / (float)BB));
    }
}

extern "C" void kernel_launch(void* const* d_in, const int* in_sizes, int n_in,
                              void* d_out, int out_size, void* d_ws, size_t ws_size,
                              hipStream_t stream) {
    const float* x       = (const float*)d_in[0];
    const int*   y       = (const int*)  d_in[1];
    const float* w       = (const float*)d_in[2];
    const float* rescale = (const float*)d_in[3];
    float* out = (float*)d_out;
    char*  wsb = (char*)d_ws;

    unsigned char* XN8 = (unsigned char*)(wsb);
    float* ZP  = (float*)(wsb + PBASE);
    float* S2P = (float*)(wsb + PBASE + P_BYTES);
    float* S3P = (float*)(wsb + PBASE + 2u * P_BYTES);
    unsigned char* WN8 = (unsigned char*)(wsb + AUX_OFF);

    k_norm_x<<<dim3(BB), dim3(256), 0, stream>>>(x, XN8, out);
    k_wnormc<<<dim3(CCPAD / 4), dim3(256), 0, stream>>>(w, WN8);
    k_gemm8 <<<dim3(8 * 391), dim3(256), 0, stream>>>(WN8, XN8, rescale, ZP, S2P, S3P);
    k_final <<<dim3(BB), dim3(256), 0, stream>>>(x, w, y, rescale, ZP, S2P, S3P, out);
}